// Round 8
// baseline (232.982 us; speedup 1.0000x reference)
//
#include <hip/hip_runtime.h>
#include <math.h>

// B=8, N=32, M=64, D=128, OUT=128, K=3, P=N*N=1024, r=512
#define EPS 1e-5f

typedef __bf16 bf16x8 __attribute__((ext_vector_type(8)));
typedef float f32x4 __attribute__((ext_vector_type(4)));

// stats layout (floats) in ws[0..1023]:
//  [0..127]   sum_sc   [128..255] sq_sc
//  [256..319] sum1     [320..383] sq1
//  [384..447] sum2     [448..511] sq2
//  [512..543] sum3     [544..575] sq3

__device__ __forceinline__ void fma4(float4& a, float s, const float4& v) {
    a.x += s * v.x; a.y += s * v.y; a.z += s * v.z; a.w += s * v.w;
}

// ---------------------------------------------------------------------------
// KCVT: Wfc1 (512x1024) and Wfc2 (1024x512) fp32 -> bf16. grid 256.
__global__ __launch_bounds__(256) void kcvt_w(
    const float* __restrict__ W1, const float* __restrict__ W2,
    __bf16* __restrict__ W1b, __bf16* __restrict__ W2b)
{
    int id = blockIdx.x * 256 + threadIdx.x;      // 0..65535
    const float* src; __bf16* dst;
    if (id < 32768) { src = W1 + (size_t)id * 16;            dst = W1b + (size_t)id * 16; }
    else            { src = W2 + (size_t)(id - 32768) * 16;  dst = W2b + (size_t)(id - 32768) * 16; }
#pragma unroll
    for (int h = 0; h < 2; h++) {
        float4 a = *(const float4*)(src + h * 8);
        float4 b = *(const float4*)(src + h * 8 + 4);
        bf16x8 v;
        v[0] = (__bf16)a.x; v[1] = (__bf16)a.y; v[2] = (__bf16)a.z; v[3] = (__bf16)a.w;
        v[4] = (__bf16)b.x; v[5] = (__bf16)b.y; v[6] = (__bf16)b.z; v[7] = (__bf16)b.w;
        *(bf16x8*)(dst + h * 8) = v;
    }
}

// ---------------------------------------------------------------------------
// K1: t_sc[b,o,n,d] = sum_m W_sc[o,m] x[b,n,m,d]; t_l1 likewise for W_l1.
// grid (3, 256). fp32 (t_l1 feeds the exact-compare corr mask -> keep fp32).
__global__ __launch_bounds__(256) void k1_w(
    const float* __restrict__ x, const float* __restrict__ Wsc,
    const float* __restrict__ Wl1, float* __restrict__ t_sc,
    float* __restrict__ t_l1, float* __restrict__ stats)
{
    int g  = blockIdx.x;
    int bn = blockIdx.y;
    int b = bn >> 5, n = bn & 31;
    __shared__ __align__(16) float s_x[64 * 128];
    __shared__ __align__(16) float s_wT[64 * 68];
    int t = threadIdx.x;

    const float4* xg = (const float4*)(x + (size_t)bn * 8192);
    for (int i = t; i < 2048; i += 256) ((float4*)s_x)[i] = xg[i];

    const float* wbase = (g < 2) ? (Wsc + (size_t)g * 64 * 64) : Wl1;
    for (int i = t; i < 1024; i += 256) {
        int m = i >> 4, rq = (i & 15) * 4;
        float4 wv;
        wv.x = wbase[(size_t)(rq + 0) * 64 + m];
        wv.y = wbase[(size_t)(rq + 1) * 64 + m];
        wv.z = wbase[(size_t)(rq + 2) * 64 + m];
        wv.w = wbase[(size_t)(rq + 3) * 64 + m];
        *(float4*)(s_wT + m * 68 + rq) = wv;
    }
    __syncthreads();

    int wv = t >> 6, lane = t & 63;
    int dl = lane & 15, g4 = lane >> 4;
    int d0 = dl * 8;
    int c0 = wv * 16 + g4 * 4;

    float4 acc[4][2];
#pragma unroll
    for (int i = 0; i < 4; i++) { acc[i][0] = make_float4(0,0,0,0); acc[i][1] = make_float4(0,0,0,0); }

    for (int m = 0; m < 64; m += 2) {
        float4 x00 = *(const float4*)(s_x + m * 128 + d0);
        float4 x01 = *(const float4*)(s_x + m * 128 + d0 + 4);
        float4 x10 = *(const float4*)(s_x + (m + 1) * 128 + d0);
        float4 x11 = *(const float4*)(s_x + (m + 1) * 128 + d0 + 4);
        float4 w0 = *(const float4*)(s_wT + m * 68 + c0);
        float4 w1 = *(const float4*)(s_wT + (m + 1) * 68 + c0);
        fma4(acc[0][0], w0.x, x00); fma4(acc[0][1], w0.x, x01);
        fma4(acc[1][0], w0.y, x00); fma4(acc[1][1], w0.y, x01);
        fma4(acc[2][0], w0.z, x00); fma4(acc[2][1], w0.z, x01);
        fma4(acc[3][0], w0.w, x00); fma4(acc[3][1], w0.w, x01);
        fma4(acc[0][0], w1.x, x10); fma4(acc[0][1], w1.x, x11);
        fma4(acc[1][0], w1.y, x10); fma4(acc[1][1], w1.y, x11);
        fma4(acc[2][0], w1.z, x10); fma4(acc[2][1], w1.z, x11);
        fma4(acc[3][0], w1.w, x10); fma4(acc[3][1], w1.w, x11);
    }

#pragma unroll
    for (int i = 0; i < 4; i++) {
        int cc = g * 64 + c0 + i;
        float4 v0 = acc[i][0], v1 = acc[i][1];
        float* dst;
        if (cc < 128) dst = t_sc + (((size_t)(b * 128 + cc)) * 32 + n) * 128 + d0;
        else          dst = t_l1 + (((size_t)(b * 64 + (cc - 128))) * 32 + n) * 128 + d0;
        *(float4*)dst = v0;
        *(float4*)(dst + 4) = v1;
        float s = v0.x + v0.y + v0.z + v0.w + v1.x + v1.y + v1.z + v1.w;
        float q = v0.x*v0.x + v0.y*v0.y + v0.z*v0.z + v0.w*v0.w
                + v1.x*v1.x + v1.y*v1.y + v1.z*v1.z + v1.w*v1.w;
#pragma unroll
        for (int off = 8; off > 0; off >>= 1) {
            s += __shfl_down(s, off, 16);
            q += __shfl_down(q, off, 16);
        }
        if (dl == 0) {
            if (cc < 128) {
                atomicAdd(&stats[cc], s);
                atomicAdd(&stats[cc + 128], q);
            } else {
                atomicAdd(&stats[256 + (cc - 128)], s);
                atomicAdd(&stats[320 + (cc - 128)], q);
            }
        }
    }
}

// ---------------------------------------------------------------------------
// K2: per (b,m) split into 2 blocks (h = half of i-rows). E written as bf16.
// grid 1024.
__global__ __launch_bounds__(256) void k2_w(
    const float* __restrict__ t_l1, const float* __restrict__ g1,
    const float* __restrict__ b1, const float* __restrict__ stats,
    float* __restrict__ y_g, __bf16* __restrict__ Ebf,
    unsigned int* __restrict__ maskbits)
{
    int blk = blockIdx.x;
    int bm = blk >> 1, h = blk & 1;
    int t  = threadIdx.x;
    __shared__ __align__(16) float y_s[32 * 132];
    __shared__ float S_s[32];
    __shared__ unsigned int m_s[16];
    int m = bm & 63;
    float mean = stats[256 + m] * (1.0f / 32768.0f);
    float var  = stats[320 + m] * (1.0f / 32768.0f) - mean * mean;
    float a = g1[m] * rsqrtf(var + EPS);
    float c = b1[m] - a * mean;

    if (t < 16) m_s[t] = 0u;
    const float4* src = (const float4*)(t_l1 + (size_t)bm * 4096);
    for (int i = t; i < 1024; i += 256) {
        float4 v = src[i];
        v.x = a * v.x + c; v.y = a * v.y + c; v.z = a * v.z + c; v.w = a * v.w + c;
        *(float4*)(y_s + (i >> 5) * 132 + (i & 31) * 4) = v;
    }
    __syncthreads();

    {
        int r = t >> 3, j = t & 7;
        float s = 0.f;
        const float* yr = y_s + r * 132 + j * 16;
#pragma unroll
        for (int dd = 0; dd < 16; dd++) s += yr[dd];
#pragma unroll
        for (int off = 4; off > 0; off >>= 1) s += __shfl_down(s, off, 8);
        if (j == 0) S_s[r] = s;
    }
    __syncthreads();

    int i_loc = t >> 4;
    int i = h * 16 + i_loc;
    int j0 = (t & 15) * 2;
    float dot0 = 0.f, dot1 = 0.f, eq0 = 0.f, eq1 = 0.f;
    const float* yi  = y_s + i * 132;
    const float* yj0 = y_s + j0 * 132;
    const float* yj1 = y_s + (j0 + 1) * 132;
    for (int dq = 0; dq < 32; dq++) {
        float4 a4 = *(const float4*)(yi + dq * 4);
        float4 b0 = *(const float4*)(yj0 + dq * 4);
        float4 b1v = *(const float4*)(yj1 + dq * 4);
        dot0 += a4.x * b0.x + a4.y * b0.y + a4.z * b0.z + a4.w * b0.w;
        eq0  += (a4.x == b0.x ? b0.x : 0.f) + (a4.y == b0.y ? b0.y : 0.f)
              + (a4.z == b0.z ? b0.z : 0.f) + (a4.w == b0.w ? b0.w : 0.f);
        dot1 += a4.x * b1v.x + a4.y * b1v.y + a4.z * b1v.z + a4.w * b1v.w;
        eq1  += (a4.x == b1v.x ? b1v.x : 0.f) + (a4.y == b1v.y ? b1v.y : 0.f)
              + (a4.z == b1v.z ? b1v.z : 0.f) + (a4.w == b1v.w ? b1v.w : 0.f);
    }
    float Si = S_s[i];
    float Sj0 = S_s[j0], Sj1 = S_s[j0 + 1];
    unsigned int bits = 0u;
    if (dot0 - Si * Sj0 * (1.0f / 128.0f) > 0.f) bits |= (1u << j0);
    if (dot1 - Si * Sj1 * (1.0f / 128.0f) > 0.f) bits |= (1u << (j0 + 1));
    float ev0 = (Si + 2.f * Sj0 - eq0) * (1.0f / 256.0f);
    float ev1 = (Si + 2.f * Sj1 - eq1) * (1.0f / 256.0f);
    atomicOr(&m_s[i_loc], bits);
    size_t eidx = (size_t)bm * 1024 + i * 32 + j0;
    Ebf[eidx]     = (__bf16)ev0;
    Ebf[eidx + 1] = (__bf16)ev1;
    __syncthreads();
    if (t < 16) maskbits[bm * 32 + h * 16 + t] = m_s[t];

    float4* yd = (float4*)(y_g + (size_t)bm * 4096);
    for (int idx = t; idx < 512; idx += 256) {
        int row = h * 16 + (idx >> 5), col = (idx & 31) * 4;
        yd[h * 512 + idx] = *(const float4*)(y_s + row * 132 + col);
    }
}

// ---------------------------------------------------------------------------
// FC1 (MFMA): H[s,r] = sum_p Ebf[s,p] * W1b[r,p].  M=512,N=512,K=1024.
// grid (8,8): 64x64 tile per block, 4 waves (16 rows each x 64 cols). No LDS.
__global__ __launch_bounds__(256) void fc1_mfma(
    const __bf16* __restrict__ Ebf, const __bf16* __restrict__ W1b,
    float* __restrict__ H)
{
    int bc = blockIdx.x * 64, br = blockIdx.y * 64;
    int t = threadIdx.x, w = t >> 6, L = t & 63;
    int lrow = L & 15, quad = L >> 4;

    const __bf16* Arow = Ebf + (size_t)(br + w * 16 + lrow) * 1024 + quad * 8;
    const __bf16* Bbase = W1b + (size_t)quad * 8;

    f32x4 acc[4] = {};
    for (int k0 = 0; k0 < 1024; k0 += 32) {
        bf16x8 a = *(const bf16x8*)(Arow + k0);
#pragma unroll
        for (int j = 0; j < 4; j++) {
            bf16x8 b = *(const bf16x8*)(Bbase + (size_t)(bc + j * 16 + lrow) * 1024 + k0);
            acc[j] = __builtin_amdgcn_mfma_f32_16x16x32_bf16(a, b, acc[j], 0, 0, 0);
        }
    }
    // D[row = quad*4+reg (within 16)][col = lrow]
#pragma unroll
    for (int j = 0; j < 4; j++) {
        int ccol = bc + j * 16 + lrow;
#pragma unroll
        for (int reg = 0; reg < 4; reg++) {
            int rrow = br + w * 16 + quad * 4 + reg;
            H[(size_t)rrow * 512 + ccol] = acc[j][reg];
        }
    }
}

// ---------------------------------------------------------------------------
// FC2 (MFMA): E2[s,p] = sigmoid( sum_r relu(H[s,r]) * W2b[p,r] ).
// M=512,N=1024,K=512. grid (16,8): 64x64 tile, 4 waves. relu+cvt on A-load.
__global__ __launch_bounds__(256) void fc2_mfma(
    const float* __restrict__ H, const __bf16* __restrict__ W2b,
    float* __restrict__ E2)
{
    int bc = blockIdx.x * 64, br = blockIdx.y * 64;
    int t = threadIdx.x, w = t >> 6, L = t & 63;
    int lrow = L & 15, quad = L >> 4;

    const float* Arow = H + (size_t)(br + w * 16 + lrow) * 512 + quad * 8;
    const __bf16* Bbase = W2b + (size_t)quad * 8;

    f32x4 acc[4] = {};
    for (int k0 = 0; k0 < 512; k0 += 32) {
        float4 h0 = *(const float4*)(Arow + k0);
        float4 h1 = *(const float4*)(Arow + k0 + 4);
        bf16x8 a;
        a[0] = (__bf16)fmaxf(h0.x, 0.f); a[1] = (__bf16)fmaxf(h0.y, 0.f);
        a[2] = (__bf16)fmaxf(h0.z, 0.f); a[3] = (__bf16)fmaxf(h0.w, 0.f);
        a[4] = (__bf16)fmaxf(h1.x, 0.f); a[5] = (__bf16)fmaxf(h1.y, 0.f);
        a[6] = (__bf16)fmaxf(h1.z, 0.f); a[7] = (__bf16)fmaxf(h1.w, 0.f);
#pragma unroll
        for (int j = 0; j < 4; j++) {
            bf16x8 b = *(const bf16x8*)(Bbase + (size_t)(bc + j * 16 + lrow) * 512 + k0);
            acc[j] = __builtin_amdgcn_mfma_f32_16x16x32_bf16(a, b, acc[j], 0, 0, 0);
        }
    }
#pragma unroll
    for (int j = 0; j < 4; j++) {
        int ccol = bc + j * 16 + lrow;
#pragma unroll
        for (int reg = 0; reg < 4; reg++) {
            int rrow = br + w * 16 + quad * 4 + reg;
            float v = acc[j][reg];
            E2[(size_t)rrow * 1024 + ccol] = 1.0f / (1.0f + expf(-v));
        }
    }
}

// ---------------------------------------------------------------------------
// K5: per (b,m) split into 2 blocks of 16 i-rows. E2 already sigmoided.
// grid 1024.
__global__ __launch_bounds__(256) void k5_w(
    const float* __restrict__ E2, const unsigned int* __restrict__ maskbits,
    const float* __restrict__ y_g, float* __restrict__ att_out,
    float* __restrict__ stats)
{
    int blk = blockIdx.x;
    int bm = blk >> 1, h = blk & 1;
    int t  = threadIdx.x;
    __shared__ __align__(16) float att_s[16 * 33];
    __shared__ __align__(16) float y_sh[32 * 128];
    __shared__ float redS[4], redQ[4];

    const float4* ysrc = (const float4*)(y_g + (size_t)bm * 4096);
    for (int i = t; i < 1024; i += 256) ((float4*)y_sh)[i] = ysrc[i];

    {
        int r_loc = t >> 4;
        int r = h * 16 + r_loc;
        int j0 = (t & 15) * 2;
        unsigned int mk = maskbits[bm * 32 + r];
        float2 e = *(const float2*)(E2 + (size_t)bm * 1024 + r * 32 + j0);
        float v0 = ((mk >> (j0 + 0)) & 1u) ? e.x : -1e12f;
        float v1 = ((mk >> (j0 + 1)) & 1u) ? e.y : -1e12f;
        float mx = fmaxf(v0, v1);
#pragma unroll
        for (int off = 1; off < 16; off <<= 1) mx = fmaxf(mx, __shfl_xor(mx, off, 16));
        float x0 = __expf(v0 - mx), x1 = __expf(v1 - mx);
        float sm = x0 + x1;
#pragma unroll
        for (int off = 1; off < 16; off <<= 1) sm += __shfl_xor(sm, off, 16);
        float inv = 1.0f / sm;
        att_s[r_loc * 33 + j0 + 0] = x0 * inv;
        att_s[r_loc * 33 + j0 + 1] = x1 * inv;
    }
    __syncthreads();

    int tx = t & 31, ty = t >> 5;
    int dq = tx * 4;
    float ssum = 0.f, sq = 0.f;
#pragma unroll
    for (int ii = 0; ii < 2; ii++) {
        int i_loc = ty * 2 + ii;
        int i = h * 16 + i_loc;
        float4 acc = make_float4(0.f, 0.f, 0.f, 0.f);
        for (int j = 0; j < 32; j++) {
            float aw = att_s[i_loc * 33 + j];
            float4 yv = *(const float4*)(y_sh + j * 128 + dq);
            acc.x += aw * yv.x; acc.y += aw * yv.y;
            acc.z += aw * yv.z; acc.w += aw * yv.w;
        }
        *(float4*)(att_out + (size_t)bm * 4096 + i * 128 + dq) = acc;
        ssum += acc.x + acc.y + acc.z + acc.w;
        sq   += acc.x * acc.x + acc.y * acc.y + acc.z * acc.z + acc.w * acc.w;
    }
#pragma unroll
    for (int off = 32; off > 0; off >>= 1) {
        ssum += __shfl_down(ssum, off, 64);
        sq   += __shfl_down(sq, off, 64);
    }
    int wave = t >> 6, lane = t & 63;
    if (lane == 0) { redS[wave] = ssum; redQ[wave] = sq; }
    __syncthreads();
    if (t == 0) {
        float S = redS[0] + redS[1] + redS[2] + redS[3];
        float Q = redQ[0] + redQ[1] + redQ[2] + redQ[3];
        int m = bm & 63;
        atomicAdd(&stats[384 + m], S);
        atomicAdd(&stats[448 + m], Q);
    }
}

// ---------------------------------------------------------------------------
// K6: per (b,n) split into 2 blocks along d (64-wide halves + 1-col halo).
// grid 512.
__global__ __launch_bounds__(256) void k6_w(
    const float* __restrict__ att_out, const float* __restrict__ Wdw,
    const float* __restrict__ g2, const float* __restrict__ b2,
    float* __restrict__ stats, float* __restrict__ v_g)
{
    int blk = blockIdx.x;
    int bn = blk >> 1, h = blk & 1;
    int b = bn >> 5, n = bn & 31;
    int dbase = h * 64;
    int t = threadIdx.x;
    __shared__ float z_s[66 * 68];
    __shared__ float a2_s[64], c2_s[64];
    __shared__ float redS[4], redQ[4];

    if (t < 64) {
        float mean = stats[384 + t] * (1.0f / 32768.0f);
        float var  = stats[448 + t] * (1.0f / 32768.0f) - mean * mean;
        float a = g2[t] * rsqrtf(var + EPS);
        a2_s[t] = a; c2_s[t] = b2[t] - a * mean;
    }
    for (int i = t; i < 66 * 68; i += 256) z_s[i] = 0.f;
    __syncthreads();

    for (int i = t; i < 1024; i += 256) {
        int m = i >> 4, c4 = (i & 15) * 4;
        float4 vv = *(const float4*)(att_out + (((size_t)(b * 64 + m)) * 32 + n) * 128 + dbase + c4);
        float a = a2_s[m], c = c2_s[m];
        float* dst = z_s + (m + 1) * 68 + 1 + c4;
        dst[0] = fmaxf(a * vv.x + c, 0.f);
        dst[1] = fmaxf(a * vv.y + c, 0.f);
        dst[2] = fmaxf(a * vv.z + c, 0.f);
        dst[3] = fmaxf(a * vv.w + c, 0.f);
    }
    if (t < 128) {
        int m = t & 63, side = t >> 6;
        int d = dbase + (side ? 64 : -1);
        if (d >= 0 && d < 128) {
            float val = att_out[(((size_t)(b * 64 + m)) * 32 + n) * 128 + d];
            z_s[(m + 1) * 68 + (side ? 65 : 0)] = fmaxf(a2_s[m] * val + c2_s[m], 0.f);
        }
    }
    float w[9];
#pragma unroll
    for (int i = 0; i < 9; i++) w[i] = Wdw[n * 9 + i];
    __syncthreads();

    int tx = t & 15, ty = t >> 4;
    int d0 = tx * 4;
    float ssum = 0.f, sq = 0.f;
#pragma unroll
    for (int rr = 0; rr < 4; rr++) {
        int hr = ty * 4 + rr;
        float o0 = 0.f, o1 = 0.f, o2 = 0.f, o3 = 0.f;
#pragma unroll
        for (int dh = 0; dh < 3; dh++) {
            const float* zr = z_s + (hr + dh) * 68 + d0;
#pragma unroll
            for (int dw = 0; dw < 3; dw++) {
                float wv = w[dh * 3 + dw];
                o0 += wv * zr[dw + 0];
                o1 += wv * zr[dw + 1];
                o2 += wv * zr[dw + 2];
                o3 += wv * zr[dw + 3];
            }
        }
        *(float4*)(v_g + ((size_t)bn * 64 + hr) * 128 + dbase + d0) = make_float4(o0, o1, o2, o3);
        ssum += o0 + o1 + o2 + o3;
        sq   += o0 * o0 + o1 * o1 + o2 * o2 + o3 * o3;
    }
#pragma unroll
    for (int off = 32; off > 0; off >>= 1) {
        ssum += __shfl_down(ssum, off, 64);
        sq   += __shfl_down(sq, off, 64);
    }
    int wave = t >> 6, lane = t & 63;
    if (lane == 0) { redS[wave] = ssum; redQ[wave] = sq; }
    __syncthreads();
    if (t == 0) {
        atomicAdd(&stats[512 + n], redS[0] + redS[1] + redS[2] + redS[3]);
        atomicAdd(&stats[544 + n], redQ[0] + redQ[1] + redQ[2] + redQ[3]);
    }
}

// ---------------------------------------------------------------------------
// K7: out[b,n,o,d] = sum_m Wl3[o,m]*relu(bn3(v[b,n,m,d])) + bn_sc(t_sc)
// grid (2, 256).
__global__ __launch_bounds__(256) void k7_w(
    const float* __restrict__ v_g, const float* __restrict__ t_sc,
    const float* __restrict__ Wl3, const float* __restrict__ g3,
    const float* __restrict__ b3, const float* __restrict__ gsc,
    const float* __restrict__ bsc, const float* __restrict__ stats,
    float* __restrict__ outp)
{
    int oh = blockIdx.x;
    int bn = blockIdx.y;
    int b = bn >> 5, n = bn & 31;
    int t = threadIdx.x;
    __shared__ __align__(16) float z_s[64 * 128];
    __shared__ __align__(16) float s_wT[64 * 68];

    float mean3 = stats[512 + n] * (1.0f / 65536.0f);
    float var3  = stats[544 + n] * (1.0f / 65536.0f) - mean3 * mean3;
    float a3 = g3[n] * rsqrtf(var3 + EPS);
    float c3 = b3[n] - a3 * mean3;

    const float4* vsrc = (const float4*)(v_g + (size_t)bn * 8192);
    for (int i = t; i < 2048; i += 256) {
        float4 vv = vsrc[i];
        float4 r;
        r.x = fmaxf(a3 * vv.x + c3, 0.f);
        r.y = fmaxf(a3 * vv.y + c3, 0.f);
        r.z = fmaxf(a3 * vv.z + c3, 0.f);
        r.w = fmaxf(a3 * vv.w + c3, 0.f);
        ((float4*)z_s)[i] = r;
    }
    const float* wbase = Wl3 + (size_t)oh * 64 * 64;
    for (int i = t; i < 1024; i += 256) {
        int m = i >> 4, rq = (i & 15) * 4;
        float4 wv;
        wv.x = wbase[(size_t)(rq + 0) * 64 + m];
        wv.y = wbase[(size_t)(rq + 1) * 64 + m];
        wv.z = wbase[(size_t)(rq + 2) * 64 + m];
        wv.w = wbase[(size_t)(rq + 3) * 64 + m];
        *(float4*)(s_wT + m * 68 + rq) = wv;
    }
    __syncthreads();

    int wv = t >> 6, lane = t & 63;
    int dl = lane & 15, g4 = lane >> 4;
    int d0 = dl * 8;
    int c0 = wv * 16 + g4 * 4;

    float4 acc[4][2];
#pragma unroll
    for (int i = 0; i < 4; i++) { acc[i][0] = make_float4(0,0,0,0); acc[i][1] = make_float4(0,0,0,0); }

    for (int m = 0; m < 64; m += 2) {
        float4 x00 = *(const float4*)(z_s + m * 128 + d0);
        float4 x01 = *(const float4*)(z_s + m * 128 + d0 + 4);
        float4 x10 = *(const float4*)(z_s + (m + 1) * 128 + d0);
        float4 x11 = *(const float4*)(z_s + (m + 1) * 128 + d0 + 4);
        float4 w0 = *(const float4*)(s_wT + m * 68 + c0);
        float4 w1 = *(const float4*)(s_wT + (m + 1) * 68 + c0);
        fma4(acc[0][0], w0.x, x00); fma4(acc[0][1], w0.x, x01);
        fma4(acc[1][0], w0.y, x00); fma4(acc[1][1], w0.y, x01);
        fma4(acc[2][0], w0.z, x00); fma4(acc[2][1], w0.z, x01);
        fma4(acc[3][0], w0.w, x00); fma4(acc[3][1], w0.w, x01);
        fma4(acc[0][0], w1.x, x10); fma4(acc[0][1], w1.x, x11);
        fma4(acc[1][0], w1.y, x10); fma4(acc[1][1], w1.y, x11);
        fma4(acc[2][0], w1.z, x10); fma4(acc[2][1], w1.z, x11);
        fma4(acc[3][0], w1.w, x10); fma4(acc[3][1], w1.w, x11);
    }

#pragma unroll
    for (int i = 0; i < 4; i++) {
        int o = oh * 64 + c0 + i;
        float msc = stats[o] * (1.0f / 32768.0f);
        float vsc = stats[128 + o] * (1.0f / 32768.0f) - msc * msc;
        float asc = gsc[o] * rsqrtf(vsc + EPS);
        float csc = bsc[o] - asc * msc;
        const float* ts = t_sc + (((size_t)(b * 128 + o)) * 32 + n) * 128 + d0;
        float4 t0 = *(const float4*)(ts);
        float4 t1 = *(const float4*)(ts + 4);
        float4 o0 = acc[i][0], o1 = acc[i][1];
        o0.x += asc * t0.x + csc; o0.y += asc * t0.y + csc;
        o0.z += asc * t0.z + csc; o0.w += asc * t0.w + csc;
        o1.x += asc * t1.x + csc; o1.y += asc * t1.y + csc;
        o1.z += asc * t1.z + csc; o1.w += asc * t1.w + csc;
        float* dst = outp + (((size_t)(b * 32 + n)) * 128 + o) * 128 + d0;
        *(float4*)dst = o0;
        *(float4*)(dst + 4) = o1;
    }
}

// ---------------------------------------------------------------------------
extern "C" void kernel_launch(void* const* d_in, const int* in_sizes, int n_in,
                              void* d_out, int out_size, void* d_ws, size_t ws_size,
                              hipStream_t stream)
{
    const float* x    = (const float*)d_in[0];
    const float* Wsc  = (const float*)d_in[1];
    const float* gsc  = (const float*)d_in[2];
    const float* bsc  = (const float*)d_in[3];
    const float* Wl1  = (const float*)d_in[4];
    const float* g1   = (const float*)d_in[5];
    const float* b1   = (const float*)d_in[6];
    const float* Wfc1 = (const float*)d_in[7];
    const float* Wfc2 = (const float*)d_in[8];
    const float* g2   = (const float*)d_in[9];
    const float* b2   = (const float*)d_in[10];
    const float* Wdw  = (const float*)d_in[11];
    const float* g3   = (const float*)d_in[12];
    const float* b3   = (const float*)d_in[13];
    const float* Wl3  = (const float*)d_in[14];
    float* outp = (float*)d_out;

    float* ws = (float*)d_ws;
    float* stats = ws;                          // 1024
    float* t_sc  = ws + 1024;                   // 4194304
    float* t_l1  = t_sc + 4194304;              // 2097152 (reused as att_out)
    float* y_g   = t_l1 + 2097152;              // 2097152 (reused as conv out)
    float* H     = y_g + 2097152;               // 262144
    float* E2    = H + 262144;                  // 524288
    __bf16* Ebf  = (__bf16*)(E2 + 524288);      // 524288 bf16 (262144 f)
    __bf16* W1b  = (__bf16*)(E2 + 524288 + 262144);            // 524288 bf16
    __bf16* W2b  = (__bf16*)(E2 + 524288 + 262144 + 262144);   // 524288 bf16
    unsigned int* maskb = (unsigned int*)(E2 + 524288 + 262144 + 524288);  // 16384 u32

    (void)hipMemsetAsync(stats, 0, 1024 * sizeof(float), stream);

    kcvt_w<<<256, 256, 0, stream>>>(Wfc1, Wfc2, W1b, W2b);
    k1_w<<<dim3(3, 256), 256, 0, stream>>>(x, Wsc, Wl1, t_sc, t_l1, stats);
    k2_w<<<1024, 256, 0, stream>>>(t_l1, g1, b1, stats, y_g, Ebf, maskb);
    fc1_mfma<<<dim3(8, 8), 256, 0, stream>>>(Ebf, W1b, H);
    fc2_mfma<<<dim3(16, 8), 256, 0, stream>>>(H, W2b, E2);
    k5_w<<<1024, 256, 0, stream>>>(E2, maskb, y_g, t_l1, stats);
    k6_w<<<512, 256, 0, stream>>>(t_l1, Wdw, g2, b2, stats, y_g);
    k7_w<<<dim3(2, 256), 256, 0, stream>>>(y_g, t_sc, Wl3, g3, b3, gsc, bsc, stats, outp);
}